// Round 7
// baseline (413.042 us; speedup 1.0000x reference)
//
#include <hip/hip_runtime.h>
#include <hip/hip_bf16.h>
#include <cstdint>
#include <cstddef>

// GATv2Conv forward, N=100000, E=1.6M, IN=128, H=4, C=32 (H*C=128).
//
// Pipeline (NO per-edge global atomics anywhere — R6 showed each device-scope
// atomicAdd costs a ~32B fabric write; 1.6M of them = 50 MB = 90 µs):
//   1) histW_k  : 8 ranges x 32 chunks; per-block LDS histogram (50 KB) of dst
//                 within its range, written coalesced to g[c][d]. Block 256 also
//                 transposes W -> bf16 Wt.
//   2) mfma_gemm_k : xl = x@W_l, xr = x@W_r via v_mfma_f32_16x16x32_bf16.
//   3) colsum_k -> scanA/B/C -> cbase_k : row_start[d] and exact per-(chunk,node)
//                 scatter bases base[c][d]. All coalesced, no atomics.
//   4) scat_k   : reload chunk, LDS cursors seeded from base, LDS atomicAdd for
//                 rank, direct store to src_sorted (range<->XCD affinity).
//   5) agg_k    : one wave per dst node, 8 edges/iter, softmax w/o max-sub.

#define NEG_SLOPE 0.2f
#define EPS_F 1e-16f
#define NRANGE 8
#define NCHUNK 32
#define MAX_RSZ 12512   // >= ceil(N/NRANGE); LDS = 50 KB

typedef __attribute__((ext_vector_type(8))) short bf16x8;
typedef __attribute__((ext_vector_type(4))) float f32x4;

static __device__ __forceinline__ unsigned f2bf(float f) {
    unsigned u = __float_as_uint(f);
    return (u + 0x7fffu + ((u >> 16) & 1u)) >> 16;   // RNE
}
static __device__ __forceinline__ float bf2f(unsigned h) {
    return __uint_as_float(h << 16);
}

// ------------- LDS-histogram pass + W transpose -------------
// block b < NRANGE*NCHUNK: r = b&7 (XCD affinity), c = b>>3.
// block b == NRANGE*NCHUNK: W[k][n] fp32 -> Wt[n][k] bf16.
__global__ __launch_bounds__(256) void histW_k(const int* __restrict__ dst, int E, int N,
                                               int rsz, int chunk_e,
                                               unsigned* __restrict__ g,
                                               const float* __restrict__ Wl,
                                               const float* __restrict__ Wr,
                                               unsigned short* __restrict__ Wtl,
                                               unsigned short* __restrict__ Wtr) {
    if (blockIdx.x == NRANGE * NCHUNK) {
        for (int mat = 0; mat < 2; ++mat) {
            const float* W = mat ? Wr : Wl;
            unsigned short* Wt = mat ? Wtr : Wtl;
            for (int i = 0; i < 64; ++i) {
                int idx = (int)threadIdx.x + i * 256;
                int k = idx >> 7, n = idx & 127;
                Wt[n * 128 + k] = (unsigned short)f2bf(W[idx]);
            }
        }
        return;
    }
    __shared__ unsigned lcnt[MAX_RSZ];
    const int r = blockIdx.x & (NRANGE - 1);
    const int c = blockIdx.x >> 3;
    const unsigned r_lo = (unsigned)(r * rsz);
    const int e0 = c * chunk_e;
    const int e1 = min(e0 + chunk_e, E);

    for (int i = threadIdx.x; i < rsz; i += 256) lcnt[i] = 0u;
    __syncthreads();
    for (int e = e0 + (int)threadIdx.x; e < e1; e += 256) {
        unsigned dd = (unsigned)dst[e] - r_lo;
        if (dd < (unsigned)rsz) atomicAdd(&lcnt[dd], 1u);   // LDS atomic
    }
    __syncthreads();
    unsigned* gc = g + (size_t)c * N + r_lo;
    int lim = min(rsz, N - (int)r_lo);
    for (int i = threadIdx.x; i < lim; i += 256) gc[i] = lcnt[i];
}

// ------------- MFMA GEMM: xl = x@Wl, xr = x@Wr (bf16 in, bf16 out) -------------
#define LROW 136
__global__ __launch_bounds__(256) void mfma_gemm_k(const float* __restrict__ A,
                                                   const unsigned short* __restrict__ Wtl,
                                                   const unsigned short* __restrict__ Wtr,
                                                   unsigned short* __restrict__ xl,
                                                   unsigned short* __restrict__ xr,
                                                   int nrows) {
    __shared__ unsigned short As[64 * LROW];
    __shared__ unsigned short Ws[128 * LROW];
    const int tid = threadIdx.x;
    const int wave = tid >> 6, lane = tid & 63;
    const int quad = lane >> 4, m16 = lane & 15;
    const int row0 = blockIdx.x * 64;

#pragma unroll
    for (int i = 0; i < 8; ++i) {
        int idx = tid + i * 256;
        int r = idx >> 5, c4 = idx & 31;
        int gr = row0 + r;
        gr = gr < nrows ? gr : nrows - 1;
        float4 v = *(const float4*)(A + (size_t)gr * 128 + c4 * 4);
        ushort4 b;
        b.x = (unsigned short)f2bf(v.x);
        b.y = (unsigned short)f2bf(v.y);
        b.z = (unsigned short)f2bf(v.z);
        b.w = (unsigned short)f2bf(v.w);
        *(ushort4*)(&As[r * LROW + c4 * 4]) = b;
    }
#pragma unroll
    for (int i = 0; i < 8; ++i) {
        int idx = tid + i * 256;
        int n = idx >> 4, kq = idx & 15;
        *(uint4*)(&Ws[n * LROW + kq * 8]) = *(const uint4*)(Wtl + n * 128 + kq * 8);
    }
    __syncthreads();

    bf16x8 af[4];
#pragma unroll
    for (int ks = 0; ks < 4; ++ks)
        af[ks] = *(const bf16x8*)(&As[(wave * 16 + m16) * LROW + ks * 32 + quad * 8]);

    f32x4 acc[8];
#pragma unroll
    for (int ct = 0; ct < 8; ++ct) acc[ct] = (f32x4){0.f, 0.f, 0.f, 0.f};
#pragma unroll
    for (int ct = 0; ct < 8; ++ct)
#pragma unroll
        for (int ks = 0; ks < 4; ++ks) {
            bf16x8 bf = *(const bf16x8*)(&Ws[(ct * 16 + m16) * LROW + ks * 32 + quad * 8]);
            acc[ct] = __builtin_amdgcn_mfma_f32_16x16x32_bf16(af[ks], bf, acc[ct], 0, 0, 0);
        }
#pragma unroll
    for (int ct = 0; ct < 8; ++ct)
#pragma unroll
        for (int r = 0; r < 4; ++r) {
            int grow = row0 + wave * 16 + quad * 4 + r;
            if (grow < nrows) xl[(size_t)grow * 128 + ct * 16 + m16] = (unsigned short)f2bf(acc[ct][r]);
        }

    __syncthreads();
#pragma unroll
    for (int i = 0; i < 8; ++i) {
        int idx = tid + i * 256;
        int n = idx >> 4, kq = idx & 15;
        *(uint4*)(&Ws[n * LROW + kq * 8]) = *(const uint4*)(Wtr + n * 128 + kq * 8);
    }
    __syncthreads();

#pragma unroll
    for (int ct = 0; ct < 8; ++ct) acc[ct] = (f32x4){0.f, 0.f, 0.f, 0.f};
#pragma unroll
    for (int ct = 0; ct < 8; ++ct)
#pragma unroll
        for (int ks = 0; ks < 4; ++ks) {
            bf16x8 bf = *(const bf16x8*)(&Ws[(ct * 16 + m16) * LROW + ks * 32 + quad * 8]);
            acc[ct] = __builtin_amdgcn_mfma_f32_16x16x32_bf16(af[ks], bf, acc[ct], 0, 0, 0);
        }
#pragma unroll
    for (int ct = 0; ct < 8; ++ct)
#pragma unroll
        for (int r = 0; r < 4; ++r) {
            int grow = row0 + wave * 16 + quad * 4 + r;
            if (grow < nrows) xr[(size_t)grow * 128 + ct * 16 + m16] = (unsigned short)f2bf(acc[ct][r]);
        }
}

// ------------- column-sum of g -> cnt -------------
__global__ __launch_bounds__(256) void colsum_k(const unsigned* __restrict__ g, int N,
                                                int* __restrict__ cnt) {
    int d = blockIdx.x * 256 + threadIdx.x;
    if (d >= N) return;
    unsigned s = 0;
#pragma unroll
    for (int c = 0; c < NCHUNK; ++c) s += g[(size_t)c * N + d];
    cnt[d] = (int)s;
}

// ---------------- 2-level scan ----------------
#define SCAN_B 256
__global__ __launch_bounds__(SCAN_B) void scanA_k(const int* __restrict__ cnt, int n,
                                                  int* __restrict__ row_start,
                                                  int* __restrict__ bsum) {
    const int tid = threadIdx.x, lane = tid & 63, wid = tid >> 6;
    const int g = blockIdx.x * SCAN_B + tid;
    int v = (g < n) ? cnt[g] : 0;
    int inc = v;
#pragma unroll
    for (int d = 1; d < 64; d <<= 1) {
        int t = __shfl_up(inc, d);
        if (lane >= d) inc += t;
    }
    __shared__ int wsum[SCAN_B / 64];
    if (lane == 63) wsum[wid] = inc;
    __syncthreads();
    int add = 0;
    for (int w = 0; w < wid; ++w) add += wsum[w];
    inc += add;
    if (g < n) row_start[g] = inc - v;
    if (tid == SCAN_B - 1) bsum[blockIdx.x] = inc;
}

__global__ __launch_bounds__(512) void scanB_k(int* __restrict__ bsum, int nb) {
    const int tid = threadIdx.x, lane = tid & 63, wid = tid >> 6;
    int v = (tid < nb) ? bsum[tid] : 0;
    int inc = v;
#pragma unroll
    for (int d = 1; d < 64; d <<= 1) {
        int t = __shfl_up(inc, d);
        if (lane >= d) inc += t;
    }
    __shared__ int wsum[8];
    if (lane == 63) wsum[wid] = inc;
    __syncthreads();
    int add = 0;
    for (int w = 0; w < wid; ++w) add += wsum[w];
    inc += add;
    if (tid < nb) bsum[tid] = inc - v;
}

__global__ __launch_bounds__(SCAN_B) void scanC_k(int* __restrict__ row_start,
                                                  const int* __restrict__ bsum,
                                                  int n, int E,
                                                  int* __restrict__ src_sorted) {
    const int g = blockIdx.x * SCAN_B + threadIdx.x;
    if (g < n) row_start[g] += bsum[blockIdx.x];
    if (g == 0) row_start[n] = E;
    if (blockIdx.x == 0 && threadIdx.x < 8) src_sorted[E + threadIdx.x] = 0;
}

// ------------- per-(chunk,node) scatter bases -------------
__global__ __launch_bounds__(256) void cbase_k(const unsigned* __restrict__ g,
                                               const int* __restrict__ row_start, int N,
                                               unsigned* __restrict__ base) {
    int d = blockIdx.x * 256 + threadIdx.x;
    if (d >= N) return;
    unsigned run = (unsigned)row_start[d];
#pragma unroll
    for (int c = 0; c < NCHUNK; ++c) {
        base[(size_t)c * N + d] = run;
        run += g[(size_t)c * N + d];
    }
}

// ------------- scatter via LDS cursors (no global atomics) -------------
__global__ __launch_bounds__(256) void scat_k(const int* __restrict__ src,
                                              const int* __restrict__ dst, int E, int N,
                                              int rsz, int chunk_e,
                                              const unsigned* __restrict__ base,
                                              int* __restrict__ src_sorted) {
    __shared__ unsigned lcur[MAX_RSZ];
    const int r = blockIdx.x & (NRANGE - 1);
    const int c = blockIdx.x >> 3;
    const unsigned r_lo = (unsigned)(r * rsz);
    const int e0 = c * chunk_e;
    const int e1 = min(e0 + chunk_e, E);

    const unsigned* bc = base + (size_t)c * N + r_lo;
    int lim = min(rsz, N - (int)r_lo);
    for (int i = threadIdx.x; i < lim; i += 256) lcur[i] = bc[i];
    __syncthreads();

    for (int e = e0 + (int)threadIdx.x; e < e1; e += 256) {
        unsigned dd = (unsigned)dst[e] - r_lo;
        if (dd < (unsigned)rsz) {
            unsigned pos = atomicAdd(&lcur[dd], 1u);   // LDS atomic
            src_sorted[pos] = src[e];
        }
    }
}

// ---------------- aggregation: one wave per dst node, 8 edges per iteration ----------------
__global__ __launch_bounds__(256) void agg_k(const unsigned* __restrict__ xlb,
                                             const unsigned* __restrict__ xrb,
                                             const float* __restrict__ att,
                                             const float* __restrict__ bias,
                                             const int* __restrict__ row_start,
                                             const int* __restrict__ src_sorted,
                                             int n, float* __restrict__ out) {
    const int wave = threadIdx.x >> 6;
    const int lane = threadIdx.x & 63;
    const int i = blockIdx.x * 4 + wave;
    if (i >= n) return;

    const int idx  = lane & 31;
    const int half = lane >> 5;

    uint2 xr2 = *(const uint2*)(xrb + (size_t)i * 64 + idx * 2);
    float xr0 = bf2f(xr2.x & 0xffffu), xr1 = bf2f(xr2.x >> 16);
    float xr2f = bf2f(xr2.y & 0xffffu), xr3 = bf2f(xr2.y >> 16);
    float4 at4 = *(const float4*)(att + idx * 4);

    const int k0 = row_start[i];
    const int k1 = row_start[i + 1];

    float l = 0.f, A0 = 0.f, A1 = 0.f, A2 = 0.f, A3 = 0.f;

    for (int k = k0; k < k1; k += 8) {
        const int kb = k + 4 * half;
        int s[4];
#pragma unroll
        for (int u = 0; u < 4; ++u) s[u] = src_sorted[kb + u];
        uint2 v[4];
#pragma unroll
        for (int u = 0; u < 4; ++u) v[u] = *(const uint2*)(xlb + (size_t)s[u] * 64 + idx * 2);
#pragma unroll
        for (int u = 0; u < 4; ++u) {
            float x0 = bf2f(v[u].x & 0xffffu), x1 = bf2f(v[u].x >> 16);
            float x2 = bf2f(v[u].y & 0xffffu), x3 = bf2f(v[u].y >> 16);
            float h0 = x0 + xr0, h1 = x1 + xr1, h2 = x2 + xr2f, h3 = x3 + xr3;
            h0 = fmaxf(h0, NEG_SLOPE * h0);
            h1 = fmaxf(h1, NEG_SLOPE * h1);
            h2 = fmaxf(h2, NEG_SLOPE * h2);
            h3 = fmaxf(h3, NEG_SLOPE * h3);
            float p = fmaf(at4.x, h0, at4.y * h1) + fmaf(at4.z, h2, at4.w * h3);
            p += __shfl_xor(p, 1);
            p += __shfl_xor(p, 2);
            p += __shfl_xor(p, 4);
            float w = (kb + u < k1) ? __expf(p) : 0.f;
            l += w;
            A0 = fmaf(w, x0, A0);
            A1 = fmaf(w, x1, A1);
            A2 = fmaf(w, x2, A2);
            A3 = fmaf(w, x3, A3);
        }
    }

    l  += __shfl_xor(l, 32);
    A0 += __shfl_xor(A0, 32);
    A1 += __shfl_xor(A1, 32);
    A2 += __shfl_xor(A2, 32);
    A3 += __shfl_xor(A3, 32);

    if (half == 0) {
        float inv = 1.f / (l + EPS_F);
        float4 b4 = *(const float4*)(bias + idx * 4);
        float4 o = {fmaf(A0, inv, b4.x), fmaf(A1, inv, b4.y),
                    fmaf(A2, inv, b4.z), fmaf(A3, inv, b4.w)};
        *(float4*)(out + (size_t)i * 128 + idx * 4) = o;
    }
}

// ---------------- launch ----------------
extern "C" void kernel_launch(void* const* d_in, const int* in_sizes, int n_in,
                              void* d_out, int out_size, void* d_ws, size_t ws_size,
                              hipStream_t stream) {
    const float* x    = (const float*)d_in[0];
    const int*   ei   = (const int*)d_in[1];
    const float* W_l  = (const float*)d_in[2];
    const float* W_r  = (const float*)d_in[3];
    const float* att  = (const float*)d_in[4];
    const float* bias = (const float*)d_in[5];
    float* out = (float*)d_out;

    const int N = in_sizes[0] / 128;
    const int E = in_sizes[1] / 2;
    const int* src = ei;
    const int* dst = ei + E;

    char* ws = (char*)d_ws;
    size_t off = 0;
    auto alloc = [&](size_t bytes) {
        void* p = ws + off;
        off += (bytes + 15) & ~(size_t)15;
        return p;
    };
    unsigned* xlb     = (unsigned*)alloc((size_t)N * 64 * 4);      // bf16 [N][128]
    unsigned* xrb     = (unsigned*)alloc((size_t)N * 64 * 4);
    unsigned* g       = (unsigned*)alloc((size_t)NCHUNK * N * 4);  // 12.8 MB
    unsigned* base    = (unsigned*)alloc((size_t)NCHUNK * N * 4);  // 12.8 MB
    int* cnt          = (int*)alloc((size_t)N * 4);
    int* row_start    = (int*)alloc((size_t)(N + 1) * 4);
    const int nsb = (N + SCAN_B - 1) / SCAN_B;
    int* bsum         = (int*)alloc((size_t)nsb * 4);
    int* src_sorted   = (int*)alloc((size_t)(E + 8) * 4);
    unsigned short* Wtl = (unsigned short*)alloc((size_t)128 * 128 * 2);
    unsigned short* Wtr = (unsigned short*)alloc((size_t)128 * 128 * 2);
    (void)ws_size;

    const int rsz = (N + NRANGE - 1) / NRANGE;          // 12500 (<= MAX_RSZ)
    const int chunk_e = (E + NCHUNK - 1) / NCHUNK;      // 50000

    histW_k<<<NRANGE * NCHUNK + 1, 256, 0, stream>>>(dst, E, N, rsz, chunk_e, g,
                                                     W_l, W_r, Wtl, Wtr);

    const int gB = (N + 63) / 64;
    mfma_gemm_k<<<gB, 256, 0, stream>>>(x, Wtl, Wtr,
                                        (unsigned short*)xlb, (unsigned short*)xrb, N);

    colsum_k<<<(N + 255) / 256, 256, 0, stream>>>(g, N, cnt);
    scanA_k<<<nsb, SCAN_B, 0, stream>>>(cnt, N, row_start, bsum);
    scanB_k<<<1, 512, 0, stream>>>(bsum, nsb);
    scanC_k<<<nsb, SCAN_B, 0, stream>>>(row_start, bsum, N, E, src_sorted);
    cbase_k<<<(N + 255) / 256, 256, 0, stream>>>(g, row_start, N, base);

    scat_k<<<NRANGE * NCHUNK, 256, 0, stream>>>(src, dst, E, N, rsz, chunk_e,
                                                base, src_sorted);

    agg_k<<<(N + 3) / 4, 256, 0, stream>>>(xlb, xrb, att, bias, row_start, src_sorted, N, out);
}

// Round 8
// 290.208 us; speedup vs baseline: 1.4233x; 1.4233x over previous
//
#include <hip/hip_runtime.h>
#include <hip/hip_bf16.h>
#include <cstdint>
#include <cstddef>

// GATv2Conv forward, N=100000, E=1.6M, IN=128, H=4, C=32 (H*C=128).
//
// Pipeline (no per-edge global atomics; R7 lesson: LDS-heavy blocks need
// 1024 threads so 2 blocks/CU = 32 waves/CU hides gather latency):
//   1) histW_k  : 8 ranges x 64 chunks, 1024-thr blocks; LDS histogram of dst
//                 within range -> g[c][d] coalesced. +1 block: W -> bf16 Wt.
//   2) mfma_gemm_k : xl = x@W_l, xr = x@W_r via v_mfma_f32_16x16x32_bf16.
//   3) colsum_k -> scanA/B/C -> cbase_k : row_start[d], base[c][d].
//   4) scat_k   : 1024-thr blocks, LDS cursors seeded from base, LDS atomicAdd,
//                 direct store (range<->XCD affinity keeps lines in one L2).
//   5) agg_k    : one wave per dst node, 8 edges/iter, softmax w/o max-sub.

#define NEG_SLOPE 0.2f
#define EPS_F 1e-16f
#define NRANGE 8
#define NCHUNK 64
#define SORT_B 1024
#define MAX_RSZ 12512   // >= ceil(N/NRANGE); LDS = 50 KB

typedef __attribute__((ext_vector_type(8))) short bf16x8;
typedef __attribute__((ext_vector_type(4))) float f32x4;

static __device__ __forceinline__ unsigned f2bf(float f) {
    unsigned u = __float_as_uint(f);
    return (u + 0x7fffu + ((u >> 16) & 1u)) >> 16;   // RNE
}
static __device__ __forceinline__ float bf2f(unsigned h) {
    return __uint_as_float(h << 16);
}

// ------------- LDS-histogram pass + W transpose -------------
__global__ __launch_bounds__(SORT_B) void histW_k(const int* __restrict__ dst, int E, int N,
                                                  int rsz, int chunk_e,
                                                  unsigned* __restrict__ g,
                                                  const float* __restrict__ Wl,
                                                  const float* __restrict__ Wr,
                                                  unsigned short* __restrict__ Wtl,
                                                  unsigned short* __restrict__ Wtr) {
    if (blockIdx.x == NRANGE * NCHUNK) {
        for (int mat = 0; mat < 2; ++mat) {
            const float* W = mat ? Wr : Wl;
            unsigned short* Wt = mat ? Wtr : Wtl;
            for (int i = 0; i < 16; ++i) {
                int idx = (int)threadIdx.x + i * SORT_B;
                int k = idx >> 7, n = idx & 127;
                Wt[n * 128 + k] = (unsigned short)f2bf(W[idx]);
            }
        }
        return;
    }
    __shared__ unsigned lcnt[MAX_RSZ];
    const int r = blockIdx.x & (NRANGE - 1);
    const int c = blockIdx.x >> 3;
    const unsigned r_lo = (unsigned)(r * rsz);
    const int e0 = c * chunk_e;
    const int e1 = min(e0 + chunk_e, E);

    for (int i = threadIdx.x; i < rsz; i += SORT_B) lcnt[i] = 0u;
    __syncthreads();
    for (int e = e0 + (int)threadIdx.x; e < e1; e += SORT_B) {
        unsigned dd = (unsigned)dst[e] - r_lo;
        if (dd < (unsigned)rsz) atomicAdd(&lcnt[dd], 1u);   // LDS atomic
    }
    __syncthreads();
    unsigned* gc = g + (size_t)c * N + r_lo;
    int lim = min(rsz, N - (int)r_lo);
    for (int i = threadIdx.x; i < lim; i += SORT_B) gc[i] = lcnt[i];
}

// ------------- MFMA GEMM: xl = x@Wl, xr = x@Wr (bf16 in, bf16 out) -------------
#define LROW 136
__global__ __launch_bounds__(256) void mfma_gemm_k(const float* __restrict__ A,
                                                   const unsigned short* __restrict__ Wtl,
                                                   const unsigned short* __restrict__ Wtr,
                                                   unsigned short* __restrict__ xl,
                                                   unsigned short* __restrict__ xr,
                                                   int nrows) {
    __shared__ unsigned short As[64 * LROW];
    __shared__ unsigned short Ws[128 * LROW];
    const int tid = threadIdx.x;
    const int wave = tid >> 6, lane = tid & 63;
    const int quad = lane >> 4, m16 = lane & 15;
    const int row0 = blockIdx.x * 64;

#pragma unroll
    for (int i = 0; i < 8; ++i) {
        int idx = tid + i * 256;
        int r = idx >> 5, c4 = idx & 31;
        int gr = row0 + r;
        gr = gr < nrows ? gr : nrows - 1;
        float4 v = *(const float4*)(A + (size_t)gr * 128 + c4 * 4);
        ushort4 b;
        b.x = (unsigned short)f2bf(v.x);
        b.y = (unsigned short)f2bf(v.y);
        b.z = (unsigned short)f2bf(v.z);
        b.w = (unsigned short)f2bf(v.w);
        *(ushort4*)(&As[r * LROW + c4 * 4]) = b;
    }
#pragma unroll
    for (int i = 0; i < 8; ++i) {
        int idx = tid + i * 256;
        int n = idx >> 4, kq = idx & 15;
        *(uint4*)(&Ws[n * LROW + kq * 8]) = *(const uint4*)(Wtl + n * 128 + kq * 8);
    }
    __syncthreads();

    bf16x8 af[4];
#pragma unroll
    for (int ks = 0; ks < 4; ++ks)
        af[ks] = *(const bf16x8*)(&As[(wave * 16 + m16) * LROW + ks * 32 + quad * 8]);

    f32x4 acc[8];
#pragma unroll
    for (int ct = 0; ct < 8; ++ct) acc[ct] = (f32x4){0.f, 0.f, 0.f, 0.f};
#pragma unroll
    for (int ct = 0; ct < 8; ++ct)
#pragma unroll
        for (int ks = 0; ks < 4; ++ks) {
            bf16x8 bf = *(const bf16x8*)(&Ws[(ct * 16 + m16) * LROW + ks * 32 + quad * 8]);
            acc[ct] = __builtin_amdgcn_mfma_f32_16x16x32_bf16(af[ks], bf, acc[ct], 0, 0, 0);
        }
#pragma unroll
    for (int ct = 0; ct < 8; ++ct)
#pragma unroll
        for (int r = 0; r < 4; ++r) {
            int grow = row0 + wave * 16 + quad * 4 + r;
            if (grow < nrows) xl[(size_t)grow * 128 + ct * 16 + m16] = (unsigned short)f2bf(acc[ct][r]);
        }

    __syncthreads();
#pragma unroll
    for (int i = 0; i < 8; ++i) {
        int idx = tid + i * 256;
        int n = idx >> 4, kq = idx & 15;
        *(uint4*)(&Ws[n * LROW + kq * 8]) = *(const uint4*)(Wtr + n * 128 + kq * 8);
    }
    __syncthreads();

#pragma unroll
    for (int ct = 0; ct < 8; ++ct) acc[ct] = (f32x4){0.f, 0.f, 0.f, 0.f};
#pragma unroll
    for (int ct = 0; ct < 8; ++ct)
#pragma unroll
        for (int ks = 0; ks < 4; ++ks) {
            bf16x8 bf = *(const bf16x8*)(&Ws[(ct * 16 + m16) * LROW + ks * 32 + quad * 8]);
            acc[ct] = __builtin_amdgcn_mfma_f32_16x16x32_bf16(af[ks], bf, acc[ct], 0, 0, 0);
        }
#pragma unroll
    for (int ct = 0; ct < 8; ++ct)
#pragma unroll
        for (int r = 0; r < 4; ++r) {
            int grow = row0 + wave * 16 + quad * 4 + r;
            if (grow < nrows) xr[(size_t)grow * 128 + ct * 16 + m16] = (unsigned short)f2bf(acc[ct][r]);
        }
}

// ------------- column-sum of g -> cnt -------------
__global__ __launch_bounds__(256) void colsum_k(const unsigned* __restrict__ g, int N,
                                                int* __restrict__ cnt) {
    int d = blockIdx.x * 256 + threadIdx.x;
    if (d >= N) return;
    unsigned s = 0;
#pragma unroll
    for (int c = 0; c < NCHUNK; ++c) s += g[(size_t)c * N + d];
    cnt[d] = (int)s;
}

// ---------------- 2-level scan ----------------
#define SCAN_B 256
__global__ __launch_bounds__(SCAN_B) void scanA_k(const int* __restrict__ cnt, int n,
                                                  int* __restrict__ row_start,
                                                  int* __restrict__ bsum) {
    const int tid = threadIdx.x, lane = tid & 63, wid = tid >> 6;
    const int g = blockIdx.x * SCAN_B + tid;
    int v = (g < n) ? cnt[g] : 0;
    int inc = v;
#pragma unroll
    for (int d = 1; d < 64; d <<= 1) {
        int t = __shfl_up(inc, d);
        if (lane >= d) inc += t;
    }
    __shared__ int wsum[SCAN_B / 64];
    if (lane == 63) wsum[wid] = inc;
    __syncthreads();
    int add = 0;
    for (int w = 0; w < wid; ++w) add += wsum[w];
    inc += add;
    if (g < n) row_start[g] = inc - v;
    if (tid == SCAN_B - 1) bsum[blockIdx.x] = inc;
}

__global__ __launch_bounds__(512) void scanB_k(int* __restrict__ bsum, int nb) {
    const int tid = threadIdx.x, lane = tid & 63, wid = tid >> 6;
    int v = (tid < nb) ? bsum[tid] : 0;
    int inc = v;
#pragma unroll
    for (int d = 1; d < 64; d <<= 1) {
        int t = __shfl_up(inc, d);
        if (lane >= d) inc += t;
    }
    __shared__ int wsum[8];
    if (lane == 63) wsum[wid] = inc;
    __syncthreads();
    int add = 0;
    for (int w = 0; w < wid; ++w) add += wsum[w];
    inc += add;
    if (tid < nb) bsum[tid] = inc - v;
}

__global__ __launch_bounds__(SCAN_B) void scanC_k(int* __restrict__ row_start,
                                                  const int* __restrict__ bsum,
                                                  int n, int E,
                                                  int* __restrict__ src_sorted) {
    const int g = blockIdx.x * SCAN_B + threadIdx.x;
    if (g < n) row_start[g] += bsum[blockIdx.x];
    if (g == 0) row_start[n] = E;
    if (blockIdx.x == 0 && threadIdx.x < 8) src_sorted[E + threadIdx.x] = 0;
}

// ------------- per-(chunk,node) scatter bases -------------
__global__ __launch_bounds__(256) void cbase_k(const unsigned* __restrict__ g,
                                               const int* __restrict__ row_start, int N,
                                               unsigned* __restrict__ base) {
    int d = blockIdx.x * 256 + threadIdx.x;
    if (d >= N) return;
    unsigned run = (unsigned)row_start[d];
#pragma unroll
    for (int c = 0; c < NCHUNK; ++c) {
        base[(size_t)c * N + d] = run;
        run += g[(size_t)c * N + d];
    }
}

// ------------- scatter via LDS cursors (no global atomics) -------------
__global__ __launch_bounds__(SORT_B) void scat_k(const int* __restrict__ src,
                                                 const int* __restrict__ dst, int E, int N,
                                                 int rsz, int chunk_e,
                                                 const unsigned* __restrict__ base,
                                                 int* __restrict__ src_sorted) {
    __shared__ unsigned lcur[MAX_RSZ];
    const int r = blockIdx.x & (NRANGE - 1);
    const int c = blockIdx.x >> 3;
    const unsigned r_lo = (unsigned)(r * rsz);
    const int e0 = c * chunk_e;
    const int e1 = min(e0 + chunk_e, E);

    const unsigned* bc = base + (size_t)c * N + r_lo;
    int lim = min(rsz, N - (int)r_lo);
    for (int i = threadIdx.x; i < lim; i += SORT_B) lcur[i] = bc[i];
    __syncthreads();

    for (int e = e0 + (int)threadIdx.x; e < e1; e += SORT_B) {
        unsigned dd = (unsigned)dst[e] - r_lo;
        if (dd < (unsigned)rsz) {
            unsigned pos = atomicAdd(&lcur[dd], 1u);   // LDS atomic
            src_sorted[pos] = src[e];
        }
    }
}

// ---------------- aggregation: one wave per dst node, 8 edges per iteration ----------------
__global__ __launch_bounds__(256) void agg_k(const unsigned* __restrict__ xlb,
                                             const unsigned* __restrict__ xrb,
                                             const float* __restrict__ att,
                                             const float* __restrict__ bias,
                                             const int* __restrict__ row_start,
                                             const int* __restrict__ src_sorted,
                                             int n, float* __restrict__ out) {
    const int wave = threadIdx.x >> 6;
    const int lane = threadIdx.x & 63;
    const int i = blockIdx.x * 4 + wave;
    if (i >= n) return;

    const int idx  = lane & 31;
    const int half = lane >> 5;

    uint2 xr2 = *(const uint2*)(xrb + (size_t)i * 64 + idx * 2);
    float xr0 = bf2f(xr2.x & 0xffffu), xr1 = bf2f(xr2.x >> 16);
    float xr2f = bf2f(xr2.y & 0xffffu), xr3 = bf2f(xr2.y >> 16);
    float4 at4 = *(const float4*)(att + idx * 4);

    const int k0 = row_start[i];
    const int k1 = row_start[i + 1];

    float l = 0.f, A0 = 0.f, A1 = 0.f, A2 = 0.f, A3 = 0.f;

    for (int k = k0; k < k1; k += 8) {
        const int kb = k + 4 * half;
        int s[4];
#pragma unroll
        for (int u = 0; u < 4; ++u) s[u] = src_sorted[kb + u];
        uint2 v[4];
#pragma unroll
        for (int u = 0; u < 4; ++u) v[u] = *(const uint2*)(xlb + (size_t)s[u] * 64 + idx * 2);
#pragma unroll
        for (int u = 0; u < 4; ++u) {
            float x0 = bf2f(v[u].x & 0xffffu), x1 = bf2f(v[u].x >> 16);
            float x2 = bf2f(v[u].y & 0xffffu), x3 = bf2f(v[u].y >> 16);
            float h0 = x0 + xr0, h1 = x1 + xr1, h2 = x2 + xr2f, h3 = x3 + xr3;
            h0 = fmaxf(h0, NEG_SLOPE * h0);
            h1 = fmaxf(h1, NEG_SLOPE * h1);
            h2 = fmaxf(h2, NEG_SLOPE * h2);
            h3 = fmaxf(h3, NEG_SLOPE * h3);
            float p = fmaf(at4.x, h0, at4.y * h1) + fmaf(at4.z, h2, at4.w * h3);
            p += __shfl_xor(p, 1);
            p += __shfl_xor(p, 2);
            p += __shfl_xor(p, 4);
            float w = (kb + u < k1) ? __expf(p) : 0.f;
            l += w;
            A0 = fmaf(w, x0, A0);
            A1 = fmaf(w, x1, A1);
            A2 = fmaf(w, x2, A2);
            A3 = fmaf(w, x3, A3);
        }
    }

    l  += __shfl_xor(l, 32);
    A0 += __shfl_xor(A0, 32);
    A1 += __shfl_xor(A1, 32);
    A2 += __shfl_xor(A2, 32);
    A3 += __shfl_xor(A3, 32);

    if (half == 0) {
        float inv = 1.f / (l + EPS_F);
        float4 b4 = *(const float4*)(bias + idx * 4);
        float4 o = {fmaf(A0, inv, b4.x), fmaf(A1, inv, b4.y),
                    fmaf(A2, inv, b4.z), fmaf(A3, inv, b4.w)};
        *(float4*)(out + (size_t)i * 128 + idx * 4) = o;
    }
}

// ---------------- launch ----------------
extern "C" void kernel_launch(void* const* d_in, const int* in_sizes, int n_in,
                              void* d_out, int out_size, void* d_ws, size_t ws_size,
                              hipStream_t stream) {
    const float* x    = (const float*)d_in[0];
    const int*   ei   = (const int*)d_in[1];
    const float* W_l  = (const float*)d_in[2];
    const float* W_r  = (const float*)d_in[3];
    const float* att  = (const float*)d_in[4];
    const float* bias = (const float*)d_in[5];
    float* out = (float*)d_out;

    const int N = in_sizes[0] / 128;
    const int E = in_sizes[1] / 2;
    const int* src = ei;
    const int* dst = ei + E;

    char* ws = (char*)d_ws;
    size_t off = 0;
    auto alloc = [&](size_t bytes) {
        void* p = ws + off;
        off += (bytes + 15) & ~(size_t)15;
        return p;
    };
    unsigned* xlb     = (unsigned*)alloc((size_t)N * 64 * 4);      // bf16 [N][128]
    unsigned* xrb     = (unsigned*)alloc((size_t)N * 64 * 4);
    unsigned* g       = (unsigned*)alloc((size_t)NCHUNK * N * 4);  // 25.6 MB
    unsigned* base    = (unsigned*)alloc((size_t)NCHUNK * N * 4);  // 25.6 MB
    int* cnt          = (int*)alloc((size_t)N * 4);
    int* row_start    = (int*)alloc((size_t)(N + 1) * 4);
    const int nsb = (N + SCAN_B - 1) / SCAN_B;
    int* bsum         = (int*)alloc((size_t)nsb * 4);
    int* src_sorted   = (int*)alloc((size_t)(E + 8) * 4);
    unsigned short* Wtl = (unsigned short*)alloc((size_t)128 * 128 * 2);
    unsigned short* Wtr = (unsigned short*)alloc((size_t)128 * 128 * 2);
    (void)ws_size;

    const int rsz = (N + NRANGE - 1) / NRANGE;          // 12500 (<= MAX_RSZ)
    const int chunk_e = (E + NCHUNK - 1) / NCHUNK;      // 25000

    histW_k<<<NRANGE * NCHUNK + 1, SORT_B, 0, stream>>>(dst, E, N, rsz, chunk_e, g,
                                                        W_l, W_r, Wtl, Wtr);

    const int gB = (N + 63) / 64;
    mfma_gemm_k<<<gB, 256, 0, stream>>>(x, Wtl, Wtr,
                                        (unsigned short*)xlb, (unsigned short*)xrb, N);

    colsum_k<<<(N + 255) / 256, 256, 0, stream>>>(g, N, cnt);
    scanA_k<<<nsb, SCAN_B, 0, stream>>>(cnt, N, row_start, bsum);
    scanB_k<<<1, 512, 0, stream>>>(bsum, nsb);
    scanC_k<<<nsb, SCAN_B, 0, stream>>>(row_start, bsum, N, E, src_sorted);
    cbase_k<<<(N + 255) / 256, 256, 0, stream>>>(g, row_start, N, base);

    scat_k<<<NRANGE * NCHUNK, SORT_B, 0, stream>>>(src, dst, E, N, rsz, chunk_e,
                                                   base, src_sorted);

    agg_k<<<(N + 3) / 4, 256, 0, stream>>>(xlb, xrb, att, bias, row_start, src_sorted, N, out);
}